// Round 4
// baseline (365.014 us; speedup 1.0000x reference)
//
#include <hip/hip_runtime.h>
#include <hip/hip_bf16.h>

#define SEQ_T 100
#define HID 20
#define EMB_D 50
#define ROWP 64          // dense table row stride (floats), gate cols [z20|r20|h20|pad4]
#define VOCAB_N 50000
#define EPW 16           // elements per wave
#define HPAD 28          // LDS h-row pad (dwords): 16B-aligned, 2-way-bank-free

typedef short sh8 __attribute__((ext_vector_type(8)));   // 8 bf16 bit-patterns
typedef float f4  __attribute__((ext_vector_type(4)));

__device__ __forceinline__ float ldf(const void* p, int i, int isf) {
  return isf ? ((const float*)p)[i]
             : __bfloat162float(((const __hip_bfloat16*)p)[i]);
}
__device__ __forceinline__ short f2bf(float f) {          // RNE fp32->bf16 bits
  unsigned u = __float_as_uint(f);
  u += 0x7fffu + ((u >> 16) & 1u);
  return (short)(u >> 16);
}
__device__ __forceinline__ float bf2f(short b) {
  return __uint_as_float(((unsigned)(unsigned short)b) << 16);
}
__device__ __forceinline__ float sigmoid_f(float x) {
  return __builtin_amdgcn_rcpf(1.f + __expf(-x));
}
__device__ __forceinline__ float tanh_f(float x) {
  return 1.f - 2.f * __builtin_amdgcn_rcpf(1.f + __expf(2.f * x));
}

// tab[v][col] = bi1[col] + sum_k emb[v][k]*W1[k][col]; fp32, 64-col rows.
// dtype self-detected: fp32 data read as u16 has uniform-random bf16-exponent
// fields (>=140 w.p. ~0.45 per low half); bf16 N(0,0.05) never exceeds ~125.
__global__ __launch_bounds__(256) void build_table(
    const void* __restrict__ emb, const void* __restrict__ W1,
    const void* __restrict__ b1, float* __restrict__ tab)
{
  const int l = threadIdx.x & 63;
  uint4 dv = ((const uint4*)emb)[l];          // 8 halfwords, same window per wave
  int big = 0;
#pragma unroll
  for (int i = 0; i < 4; ++i) {
    unsigned w = ((const unsigned*)&dv)[i];
    big |= (((w >> 7) & 0xFF) >= 140) | (((w >> 23) & 0xFF) >= 140);
  }
  const int isf = (__ballot(big) != 0ull) ? 1 : 0;

  const int pr = blockIdx.x * 4 + (threadIdx.x >> 6);
  const int v0 = pr * 2;
  if (v0 >= VOCAB_N) return;
  const int jc = l < 60 ? l : 0;
  float bias = ldf(b1, jc, isf);
  float a0 = bias, a1 = bias;
#pragma unroll 5
  for (int k = 0; k < EMB_D; k += 2) {
    float w0 = ldf(W1, k * 60 + jc, isf);
    float w1 = ldf(W1, (k + 1) * 60 + jc, isf);
    float e00, e01, e10, e11;
    if (isf) {
      const float* ef = (const float*)emb;
      float2 f0 = *(const float2*)(ef + v0 * EMB_D + k);
      float2 f1 = *(const float2*)(ef + (v0 + 1) * EMB_D + k);
      e00 = f0.x; e01 = f0.y; e10 = f1.x; e11 = f1.y;
    } else {
      const unsigned short* eh = (const unsigned short*)emb;
      unsigned u0 = *(const unsigned*)(eh + v0 * EMB_D + k);
      unsigned u1 = *(const unsigned*)(eh + (v0 + 1) * EMB_D + k);
      e00 = __uint_as_float(u0 << 16); e01 = __uint_as_float(u0 & 0xffff0000u);
      e10 = __uint_as_float(u1 << 16); e11 = __uint_as_float(u1 & 0xffff0000u);
    }
    a0 = fmaf(e00, w0, a0); a0 = fmaf(e01, w1, a0);
    a1 = fmaf(e10, w0, a1); a1 = fmaf(e11, w1, a1);
  }
  float w0 = (l < 60) ? a0 : 0.f, w1 = (l < 60) ? a1 : 0.f;
  tab[(size_t)v0 * ROWP + l] = w0;
  tab[(size_t)(v0 + 1) * ROWP + l] = w1;
}

// One wave / block, 16 elements / wave. Recurrent matvecs via
// mfma_f32_16x16x32_bf16 over 6 N-tiles (96 padded gate cols: [z|pad|r|pad|h|pad]
// so z_i/r_i/hc_i share a lane+reg). h fp32 master, hi/lo bf16 split (2 MFMA/tile).
// A-layout: A[m=lane&15][k=quad*8+j]; B: B[k=quad*8+j][n=lane&15];
// C: row(elem)=(quad*4+reg), col=lane&15.
__global__ __launch_bounds__(64, 1) void gru_main(
    const int* __restrict__ x, const float* __restrict__ tab,
    const void* __restrict__ emb,
    const void* __restrict__ U1, const void* __restrict__ b1,
    const void* __restrict__ W2, const void* __restrict__ U2,
    const void* __restrict__ b2, const void* __restrict__ Wd,
    const void* __restrict__ bd, void* __restrict__ out)
{
  const int L = threadIdx.x, q = L >> 4, c = L & 15;
  const int e0 = blockIdx.x * EPW;

  // dtype self-detect (same method as build_table)
  uint4 dv = ((const uint4*)emb)[L];
  int big = 0;
#pragma unroll
  for (int i = 0; i < 4; ++i) {
    unsigned w = ((const unsigned*)&dv)[i];
    big |= (((w >> 7) & 0xFF) >= 140) | (((w >> 23) & 0xFF) >= 140);
  }
  const int isf = (__ballot(big) != 0ull) ? 1 : 0;

  // ---- weight B-frags + bias col-constants ----
  sh8 BU1[6], BW2[6], BU2[6];
  float brc1[6], bi2c[6], br2c[6];
#pragma unroll
  for (int tau = 0; tau < 6; ++tau) {
    const int g = tau >> 1, i = ((tau & 1) << 4) + c;
    const bool vc = i < HID;
    const int col = 20 * g + i;
    brc1[tau] = vc ? ldf(b1, 60 + col, isf) : 0.f;
    bi2c[tau] = vc ? ldf(b2, col, isf) : 0.f;
    br2c[tau] = vc ? ldf(b2, 60 + col, isf) : 0.f;
    sh8 u1, w2, u2;
#pragma unroll
    for (int j = 0; j < 8; ++j) {
      const int k = q * 8 + j;
      const bool vk = vc && (k < HID);
      u1[j] = vk ? f2bf(ldf(U1, k * 60 + col, isf)) : (short)0;
      w2[j] = vk ? f2bf(ldf(W2, k * 60 + col, isf)) : (short)0;
      u2[j] = vk ? f2bf(ldf(U2, k * 60 + col, isf)) : (short)0;
    }
    BU1[tau] = u1; BW2[tau] = w2; BU2[tau] = u2;
  }

  // ---- LDS ----
  __shared__ int   xbuf[EPW * SEQ_T];               // 6.4 KB
  __shared__ float h1buf[EPW * HPAD], h2buf[EPW * HPAD];
  {
    const uint4* xs = (const uint4*)(x + (size_t)e0 * SEQ_T);
    uint4* xd = (uint4*)xbuf;
#pragma unroll
    for (int m = L; m < (EPW * SEQ_T) / 4; m += 64) xd[m] = xs[m];
#pragma unroll
    for (int m = L; m < EPW * HPAD; m += 64) { h1buf[m] = 0.f; h2buf[m] = 0.f; }
  }
  __syncthreads();   // single wave: cheap; orders LDS init

  sh8 a1hi = {0,0,0,0,0,0,0,0}, a1lo = a1hi, a2hi = a1hi, a2lo = a1hi;
  f4 h1C[2], h2C[2];
#pragma unroll
  for (int p = 0; p < 2; ++p) { h1C[p] = (f4)0.f; h2C[p] = (f4)0.f; }

  // ---- initial gather: mx(t=0) in C-space, padded tiles ----
  f4 mxc[6];
  int rowc[4];
#pragma unroll
  for (int r = 0; r < 4; ++r) rowc[r] = xbuf[(q * 4 + r) * SEQ_T + 0];
#pragma unroll
  for (int tau = 0; tau < 6; ++tau) {
    const int g = tau >> 1;
    const bool odd = tau & 1;
    const int dcol = 20 * g + (odd ? 16 : 0) + c;
#pragma unroll
    for (int r = 0; r < 4; ++r) {
      float v = 0.f;
      if (!odd || c < 4) v = tab[(size_t)rowc[r] * ROWP + dcol];
      mxc[tau][r] = v;
    }
  }

#pragma unroll 1
  for (int t = 0; t < SEQ_T; ++t) {
    // prefetch mx(t+1)
    f4 mxn[6];
    if (t + 1 < SEQ_T) {
      int rown[4];
#pragma unroll
      for (int r = 0; r < 4; ++r) rown[r] = xbuf[(q * 4 + r) * SEQ_T + t + 1];
#pragma unroll
      for (int tau = 0; tau < 6; ++tau) {
        const int g = tau >> 1;
        const bool odd = tau & 1;
        const int dcol = 20 * g + (odd ? 16 : 0) + c;
#pragma unroll
        for (int r = 0; r < 4; ++r) {
          float v = 0.f;
          if (!odd || c < 4) v = tab[(size_t)rown[r] * ROWP + dcol];
          mxn[tau][r] = v;
        }
      }
    }

    // ---- GRU1: mh = h1 @ U1 + br1 ----
    f4 acc1[6];
#pragma unroll
    for (int tau = 0; tau < 6; ++tau) {
      f4 a = { brc1[tau], brc1[tau], brc1[tau], brc1[tau] };
      a = __builtin_amdgcn_mfma_f32_16x16x32_bf16(a1lo, BU1[tau], a, 0, 0, 0);
      a = __builtin_amdgcn_mfma_f32_16x16x32_bf16(a1hi, BU1[tau], a, 0, 0, 0);
      acc1[tau] = a;
    }
    // gates layer 1 (z,r,hc aligned per lane/reg; p=1 valid only c<4)
#pragma unroll
    for (int p = 0; p < 2; ++p) {
      const bool valid = (p == 0) || (c < 4);
#pragma unroll
      for (int r = 0; r < 4; ++r) {
        float z  = sigmoid_f(mxc[0 + p][r] + acc1[0 + p][r]);
        float rr = sigmoid_f(mxc[2 + p][r] + acc1[2 + p][r]);
        float hc = tanh_f(fmaf(rr, acc1[4 + p][r], mxc[4 + p][r]));
        float hn = fmaf(z, h1C[p][r] - hc, hc);
        h1C[p][r] = hn;
        if (valid) h1buf[(q * 4 + r) * HPAD + c + 16 * p] = hn;
      }
    }
    // rebuild h1 A-frags (fp32 -> hi/lo bf16), C->A transpose via LDS
    {
      sh8 hi = {0,0,0,0,0,0,0,0}, lo = hi;
      if (q < 3) {
        const f4* hp = (const f4*)&h1buf[c * HPAD + q * 8];
        f4 v0 = hp[0], v1 = hp[1];
#pragma unroll
        for (int j = 0; j < 4; ++j) {
          short h0 = f2bf(v0[j]); hi[j] = h0; lo[j] = f2bf(v0[j] - bf2f(h0));
          short h1 = f2bf(v1[j]); hi[4 + j] = h1; lo[4 + j] = f2bf(v1[j] - bf2f(h1));
        }
      }
      a1hi = hi; a1lo = lo;
    }

    // ---- GRU2: mx2 = h1new @ W2 + bi2 ; mh2 = h2 @ U2 + br2 ----
    f4 accA[6], accB[6];
#pragma unroll
    for (int tau = 0; tau < 6; ++tau) {
      f4 a = { bi2c[tau], bi2c[tau], bi2c[tau], bi2c[tau] };
      a = __builtin_amdgcn_mfma_f32_16x16x32_bf16(a1lo, BW2[tau], a, 0, 0, 0);
      a = __builtin_amdgcn_mfma_f32_16x16x32_bf16(a1hi, BW2[tau], a, 0, 0, 0);
      accA[tau] = a;
      f4 b = { br2c[tau], br2c[tau], br2c[tau], br2c[tau] };
      b = __builtin_amdgcn_mfma_f32_16x16x32_bf16(a2lo, BU2[tau], b, 0, 0, 0);
      b = __builtin_amdgcn_mfma_f32_16x16x32_bf16(a2hi, BU2[tau], b, 0, 0, 0);
      accB[tau] = b;
    }
#pragma unroll
    for (int p = 0; p < 2; ++p) {
      const bool valid = (p == 0) || (c < 4);
#pragma unroll
      for (int r = 0; r < 4; ++r) {
        float z  = sigmoid_f(accA[0 + p][r] + accB[0 + p][r]);
        float rr = sigmoid_f(accA[2 + p][r] + accB[2 + p][r]);
        float hc = tanh_f(fmaf(rr, accB[4 + p][r], accA[4 + p][r]));
        float hn = fmaf(z, h2C[p][r] - hc, hc);
        h2C[p][r] = hn;
        if (valid) h2buf[(q * 4 + r) * HPAD + c + 16 * p] = hn;
      }
    }
    if (t + 1 < SEQ_T) {
      sh8 hi = {0,0,0,0,0,0,0,0}, lo = hi;
      if (q < 3) {
        const f4* hp = (const f4*)&h2buf[c * HPAD + q * 8];
        f4 v0 = hp[0], v1 = hp[1];
#pragma unroll
        for (int j = 0; j < 4; ++j) {
          short h0 = f2bf(v0[j]); hi[j] = h0; lo[j] = f2bf(v0[j] - bf2f(h0));
          short h1 = f2bf(v1[j]); hi[4 + j] = h1; lo[4 + j] = f2bf(v1[j] - bf2f(h1));
        }
      }
      a2hi = hi; a2lo = lo;
#pragma unroll
      for (int tau = 0; tau < 6; ++tau) mxc[tau] = mxn[tau];
    }
  }

  // ---- dense epilogue: logits = h2 @ Wd + bd (h2 fp32 in h2buf) ----
#pragma unroll
  for (int o = L; o < EPW * 15; o += 64) {
    const int e = o / 15, lbl = o % 15;
    float a = ldf(bd, lbl, isf);
#pragma unroll
    for (int k = 0; k < HID; ++k)
      a = fmaf(h2buf[e * HPAD + k], ldf(Wd, k * 15 + lbl, isf), a);
    if (isf) ((float*)out)[(size_t)(e0 + e) * 15 + lbl] = a;
    else ((__hip_bfloat16*)out)[(size_t)(e0 + e) * 15 + lbl] = __float2bfloat16(a);
  }
}

extern "C" void kernel_launch(void* const* d_in, const int* in_sizes, int n_in,
                              void* d_out, int out_size, void* d_ws, size_t ws_size,
                              hipStream_t stream) {
  const int* x    = (const int*)d_in[0];
  const void* emb = d_in[1];
  const void* W1  = d_in[2];
  const void* U1  = d_in[3];
  const void* b1  = d_in[4];
  const void* W2  = d_in[5];
  const void* U2  = d_in[6];
  const void* b2  = d_in[7];
  const void* Wd  = d_in[8];
  const void* bd  = d_in[9];
  float* tab = (float*)d_ws;   // 50000*64*4 = 12.8 MB

  build_table<<<VOCAB_N / 8, 256, 0, stream>>>(emb, W1, b1, tab);
  gru_main<<<8192 / EPW, 64, 0, stream>>>(x, tab, emb, U1, b1, W2, U2, b2,
                                          Wd, bd, d_out);
}

// Round 5
// 331.826 us; speedup vs baseline: 1.1000x; 1.1000x over previous
//
#include <hip/hip_runtime.h>
#include <hip/hip_bf16.h>

#define SEQ_T 100
#define HID 20
#define EMB_D 50
#define ROWP 64          // tab row stride (floats): gate cols [z20|r20|h20|pad4=0]
#define VOCAB_N 50000

__device__ __forceinline__ float ldf(const void* p, int i, int isf) {
  return isf ? ((const float*)p)[i]
             : __bfloat162float(((const __hip_bfloat16*)p)[i]);
}
// broadcast lane l's value into an SGPR (wave-uniform)
__device__ __forceinline__ float rdl(float v, int l) {
  return __uint_as_float(__builtin_amdgcn_readlane(__float_as_uint(v), l));
}
__device__ __forceinline__ float sigmoid_f(float x) {
  return __builtin_amdgcn_rcpf(1.f + __expf(-x));
}
__device__ __forceinline__ float tanh_f(float x) {
  return 1.f - 2.f * __builtin_amdgcn_rcpf(1.f + __expf(2.f * x));
}
// fp32 data read as u16 halfwords has uniform-random bf16-exponent fields
// (>=140 w.p. ~0.45 per low half); bf16 N(0,0.05) never exceeds ~125.
__device__ __forceinline__ int detect_isf(const void* emb) {
  uint4 dv = ((const uint4*)emb)[threadIdx.x & 63];
  int big = 0;
#pragma unroll
  for (int i = 0; i < 4; ++i) {
    unsigned w = ((const unsigned*)&dv)[i];
    big |= (((w >> 7) & 0xFF) >= 140) | (((w >> 23) & 0xFF) >= 140);
  }
  return (__ballot(big) != 0ull) ? 1 : 0;
}

// tab[v][col] = bi1[col] + sum_k emb[v][k]*W1[k][col]; fp32, 64-col rows.
__global__ __launch_bounds__(256) void build_table(
    const void* __restrict__ emb, const void* __restrict__ W1,
    const void* __restrict__ b1, float* __restrict__ tab)
{
  const int isf = detect_isf(emb);
  const int l = threadIdx.x & 63;
  const int pr = blockIdx.x * 4 + (threadIdx.x >> 6);
  const int v0 = pr * 2;
  if (v0 >= VOCAB_N) return;
  const int jc = l < 60 ? l : 0;
  float bias = ldf(b1, jc, isf);
  float a0 = bias, a1 = bias;
#pragma unroll 5
  for (int k = 0; k < EMB_D; k += 2) {
    float w0 = ldf(W1, k * 60 + jc, isf);
    float w1 = ldf(W1, (k + 1) * 60 + jc, isf);
    float e00, e01, e10, e11;
    if (isf) {
      const float* ef = (const float*)emb;
      float2 f0 = *(const float2*)(ef + v0 * EMB_D + k);
      float2 f1 = *(const float2*)(ef + (v0 + 1) * EMB_D + k);
      e00 = f0.x; e01 = f0.y; e10 = f1.x; e11 = f1.y;
    } else {
      const unsigned short* eh = (const unsigned short*)emb;
      unsigned u0 = *(const unsigned*)(eh + v0 * EMB_D + k);
      unsigned u1 = *(const unsigned*)(eh + (v0 + 1) * EMB_D + k);
      e00 = __uint_as_float(u0 << 16); e01 = __uint_as_float(u0 & 0xffff0000u);
      e10 = __uint_as_float(u1 << 16); e11 = __uint_as_float(u1 & 0xffff0000u);
    }
    a0 = fmaf(e00, w0, a0); a0 = fmaf(e01, w1, a0);
    a1 = fmaf(e10, w0, a1); a1 = fmaf(e11, w1, a1);
  }
  tab[(size_t)v0 * ROWP + l]       = (l < 60) ? a0 : 0.f;
  tab[(size_t)(v0 + 1) * ROWP + l] = (l < 60) ? a1 : 0.f;
}

// ONE batch element per wave; lane j<60 owns gate column j (z|r|h).
// Register budget (sized to FIT, the round-3 killer): 60 weight VGPRs +
// ~30 temps < 128 (4 waves/SIMD); h-state = 40 readlane-born SGPRs.
// Matvecs: v_fma with SGPR h-operand x VGPR weight. Gate exchange: 2
// bpermutes/layer. Zero LDS data staging, zero __syncthreads.
__global__ __launch_bounds__(256, 4) void gru_main(
    const int* __restrict__ x, const float* __restrict__ tab,
    const void* __restrict__ emb,
    const void* __restrict__ U1, const void* __restrict__ b1,
    const void* __restrict__ W2, const void* __restrict__ U2,
    const void* __restrict__ b2, const void* __restrict__ Wd,
    const void* __restrict__ bd, void* __restrict__ out)
{
  const int isf = detect_isf(emb);
  const int j = threadIdx.x & 63;
  const int e = blockIdx.x * 4 + (threadIdx.x >> 6);
  const int jc = j < 60 ? j : 0;

  float wU1[HID], wW2[HID], wU2[HID];
#pragma unroll
  for (int k = 0; k < HID; ++k) {
    wU1[k] = ldf(U1, k * 60 + jc, isf);
    wW2[k] = ldf(W2, k * 60 + jc, isf);
    wU2[k] = ldf(U2, k * 60 + jc, isf);
  }
  const float br1 = ldf(b1, 60 + jc, isf);
  const float bi2 = ldf(b2, jc, isf);
  const float br2 = ldf(b2, 60 + jc, isf);

  float s1[HID], s2[HID];            // wave-uniform h (SGPRs via readlane)
#pragma unroll
  for (int k = 0; k < HID; ++k) { s1[k] = 0.f; s2[k] = 0.f; }
  float h1v = 0.f, h2v = 0.f;        // own-lane h copy (lanes 0..19)

  const int* __restrict__ xr = x + (size_t)e * SEQ_T;
  const float* __restrict__ tb = tab + j;

  // 2-deep pipelined input-transform gather
  float mx0 = tb[(size_t)xr[0] * ROWP];
  float mx1 = tb[(size_t)xr[1] * ROWP];

#pragma unroll 1
  for (int t = 0; t < SEQ_T; ++t) {
    float mx = mx0;
    mx0 = mx1;
    if (t + 2 < SEQ_T) mx1 = tb[(size_t)xr[t + 2] * ROWP];

    // ---- GRU1: mh = h1 @ U1 + br1 ----
    float mh = br1;
#pragma unroll
    for (int k = 0; k < HID; ++k) mh = fmaf(s1[k], wU1[k], mh);
    float g  = sigmoid_f(mx + mh);          // z (lanes 0..19), r (20..39)
    float rr = __shfl(g, j - 20);           // h-lanes (40..59) fetch r
    float hc = tanh_f(fmaf(rr, mh, mx));    // xh + r*(h@U_h + br_h)
    float hv = __shfl(hc, j + 40);          // z-lanes fetch hcand
    h1v = fmaf(g, h1v - hv, hv);            // z*h + (1-z)*hc, lanes 0..19
#pragma unroll
    for (int k = 0; k < HID; ++k) s1[k] = rdl(h1v, k);

    // ---- GRU2: mx2 = h1new @ W2 + bi2 ; mh2 = h2 @ U2 + br2 ----
    float m2 = bi2, n2 = br2;
#pragma unroll
    for (int k = 0; k < HID; ++k) {
      m2 = fmaf(s1[k], wW2[k], m2);
      n2 = fmaf(s2[k], wU2[k], n2);
    }
    float g2  = sigmoid_f(m2 + n2);
    float rr2 = __shfl(g2, j - 20);
    float hc2 = tanh_f(fmaf(rr2, n2, m2));
    float hv2 = __shfl(hc2, j + 40);
    h2v = fmaf(g2, h2v - hv2, hv2);
#pragma unroll
    for (int k = 0; k < HID; ++k) s2[k] = rdl(h2v, k);
  }

  // ---- dense: logits = h2 @ Wd + bd (h2 wave-uniform in SGPRs) ----
  if (j < 15) {
    float a = ldf(bd, j, isf);
#pragma unroll
    for (int k = 0; k < HID; ++k)
      a = fmaf(s2[k], ldf(Wd, k * 15 + j, isf), a);
    if (isf) ((float*)out)[(size_t)e * 15 + j] = a;
    else ((__hip_bfloat16*)out)[(size_t)e * 15 + j] = __float2bfloat16(a);
  }
}

extern "C" void kernel_launch(void* const* d_in, const int* in_sizes, int n_in,
                              void* d_out, int out_size, void* d_ws, size_t ws_size,
                              hipStream_t stream) {
  const int* x    = (const int*)d_in[0];
  const void* emb = d_in[1];
  const void* W1  = d_in[2];
  const void* U1  = d_in[3];
  const void* b1  = d_in[4];
  const void* W2  = d_in[5];
  const void* U2  = d_in[6];
  const void* b2  = d_in[7];
  const void* Wd  = d_in[8];
  const void* bd  = d_in[9];
  float* tab = (float*)d_ws;   // 50000*64*4 = 12.8 MB

  build_table<<<VOCAB_N / 8, 256, 0, stream>>>(emb, W1, b1, tab);
  // 8192 waves, 1 element each; 4 waves per 256-thread block
  gru_main<<<8192 / 4, 256, 0, stream>>>(x, tab, emb, U1, b1, W2, U2, b2,
                                         Wd, bd, d_out);
}